// Round 11
// baseline (355.867 us; speedup 1.0000x reference)
//
#include <hip/hip_runtime.h>

// Shapes (fixed per setup_inputs): n=1, C=256, t=8, h=64, w=64, heads=8, S=134
#define SS   134
#define HWP  4096     // h*w
#define THW  32768    // t*h*w

typedef float f32x4 __attribute__((ext_vector_type(4)));
typedef short bf16x8 __attribute__((ext_vector_type(8)));
typedef short bf16x4 __attribute__((ext_vector_type(4)));

__device__ __forceinline__ unsigned short f2bf(float f) {
  unsigned int u = __float_as_uint(f);
  u += 0x7fff + ((u >> 16) & 1);  // RNE (inputs are finite normals)
  return (unsigned short)(u >> 16);
}

// ---------------------------------------------------------------------------
// W -> bf16, once. Wbf lives in d_out (128 KB): attn_tw fully overwrites O
// afterwards; stream order (w2bf -> conv -> attn_tw) makes aliasing safe.
// ---------------------------------------------------------------------------
__global__ __launch_bounds__(256) void w2bf(const float* __restrict__ W,
                                            unsigned short* __restrict__ Wbf) {
  const int i = (blockIdx.x * 256 + threadIdx.x) * 4;  // grid 64 -> 65536
  const float4 w4 = *(const float4*)&W[i];
  bf16x4 b;
  b.x = (short)f2bf(w4.x);
  b.y = (short)f2bf(w4.y);
  b.z = (short)f2bf(w4.z);
  b.w = (short)f2bf(w4.w);
  *(bf16x4*)&Wbf[i] = b;
}

// ---------------------------------------------------------------------------
// 1x1 conv v4 (unchanged): W staged once into 130KB LDS, V dbuf.
// ---------------------------------------------------------------------------
__global__ __launch_bounds__(512) void conv1x1_v4(
    const float* __restrict__ V, const unsigned short* __restrict__ Wbf,
    const float* __restrict__ bias, float* __restrict__ PV) {
  __shared__ unsigned short sW[256 * 260];   // 130 KB, row stride 260
  __shared__ unsigned short sV[2][128 * 40]; // [buf][x][c], 2 x 10 KB
  const int tid = threadIdx.x;
  const int x0 = blockIdx.x * 128;  // grid 256
  const int lane = tid & 63;
  const int wv = tid >> 6;   // 0..7
  const int m = lane & 15;   // MFMA free-dim index
  const int q = lane >> 4;   // MFMA quad 0..3

  {
    const int o = tid >> 1;
    const int half = (tid & 1) * 128;
#pragma unroll
    for (int r = 0; r < 16; ++r)
      *(bf16x8*)&sW[o * 260 + half + r * 8] =
          *(const bf16x8*)&Wbf[o * 256 + half + r * 8];
  }

  const int c_s = tid >> 4;
  const int x8 = (tid & 15) * 8;
  const float* __restrict__ vstage = V + (size_t)c_s * THW + x0 + x8;

  {
    const float4 va = *(const float4*)&vstage[0];
    const float4 vb = *(const float4*)&vstage[4];
    sV[0][(x8 + 0) * 40 + c_s] = f2bf(va.x);
    sV[0][(x8 + 1) * 40 + c_s] = f2bf(va.y);
    sV[0][(x8 + 2) * 40 + c_s] = f2bf(va.z);
    sV[0][(x8 + 3) * 40 + c_s] = f2bf(va.w);
    sV[0][(x8 + 4) * 40 + c_s] = f2bf(vb.x);
    sV[0][(x8 + 5) * 40 + c_s] = f2bf(vb.y);
    sV[0][(x8 + 6) * 40 + c_s] = f2bf(vb.z);
    sV[0][(x8 + 7) * 40 + c_s] = f2bf(vb.w);
  }
  __syncthreads();

  f32x4 acc[2][8];
#pragma unroll
  for (int i = 0; i < 2; ++i)
#pragma unroll
    for (int j = 0; j < 8; ++j)
      acc[i][j] = (f32x4){0.f, 0.f, 0.f, 0.f};

  for (int kk = 0; kk < 8; ++kk) {
    const int cur = kk & 1;
    float4 pva, pvb;
    if (kk < 7) {
      pva = *(const float4*)&vstage[(size_t)(kk + 1) * 32 * THW];
      pvb = *(const float4*)&vstage[(size_t)(kk + 1) * 32 * THW + 4];
    }
    bf16x8 fa[2], fb[8];
#pragma unroll
    for (int i = 0; i < 2; ++i)
      fa[i] = *(const bf16x8*)&sW[(wv * 32 + i * 16 + m) * 260 + kk * 32 + q * 8];
#pragma unroll
    for (int j = 0; j < 8; ++j)
      fb[j] = *(const bf16x8*)&sV[cur][(j * 16 + m) * 40 + q * 8];
#pragma unroll
    for (int i = 0; i < 2; ++i)
#pragma unroll
      for (int j = 0; j < 8; ++j)
        acc[i][j] = __builtin_amdgcn_mfma_f32_16x16x32_bf16(fa[i], fb[j], acc[i][j], 0, 0, 0);
    if (kk < 7) {
      const int nb = cur ^ 1;
      sV[nb][(x8 + 0) * 40 + c_s] = f2bf(pva.x);
      sV[nb][(x8 + 1) * 40 + c_s] = f2bf(pva.y);
      sV[nb][(x8 + 2) * 40 + c_s] = f2bf(pva.z);
      sV[nb][(x8 + 3) * 40 + c_s] = f2bf(pva.w);
      sV[nb][(x8 + 4) * 40 + c_s] = f2bf(pvb.x);
      sV[nb][(x8 + 5) * 40 + c_s] = f2bf(pvb.y);
      sV[nb][(x8 + 6) * 40 + c_s] = f2bf(pvb.z);
      sV[nb][(x8 + 7) * 40 + c_s] = f2bf(pvb.w);
    }
    __syncthreads();
  }

#pragma unroll
  for (int i = 0; i < 2; ++i) {
#pragma unroll
    for (int r = 0; r < 4; ++r) {
      const int o = wv * 32 + i * 16 + q * 4 + r;
      const float bo = bias[o];
#pragma unroll
      for (int j = 0; j < 8; ++j)
        PV[(size_t)o * THW + x0 + j * 16 + m] = acc[i][j][r] + bo;
    }
  }
}

// ---------------------------------------------------------------------------
// t + w fused (R10 structure), writes O once. Only change: unroll hint on
// the s-loop for deeper load pipelining (all loads independent).
// ---------------------------------------------------------------------------
__global__ __launch_bounds__(256) void attn_tw(
    const float* __restrict__ A, const float* __restrict__ PV,
    float* __restrict__ O) {
  const int b = blockIdx.x;  // hb + 16*tq + 128*hd, grid 1024
  const int hb = b & 15;
  const int tq = (b >> 4) & 7;
  const int hd = b >> 7;
  const int tid = threadIdx.x;
  const int wq = tid & 63;
  const int cg = tid >> 6;  // 0..3
  const int h0 = hb * 4;

  __shared__ float slab[32 * 64 * 4];  // [c][pw][h4] = 32 KB

  const float* __restrict__ Ab = A + (size_t)hd * SS * THW + (size_t)tq * HWP;
  const size_t pvh = (size_t)hd * 32 * THW;

  // ---- stage pv w-slab (transpose w<->h minor dims), c = 0..31 ----
#pragma unroll
  for (int i = 0; i < 8; ++i) {
    const int fid = tid + i * 256;     // 0..2047
    const int w4s = (fid & 15) * 4;    // 0..60
    const int h = (fid >> 4) & 3;      // 0..3
    const int c = fid >> 6;            // 0..31
    const f32x4 v =
        *(const f32x4*)&PV[pvh + (size_t)c * THW + (size_t)tq * HWP + (h0 + h) * 64 + w4s];
    slab[(c * 64 + w4s + 0) * 4 + h] = v.x;
    slab[(c * 64 + w4s + 1) * 4 + h] = v.y;
    slab[(c * 64 + w4s + 2) * 4 + h] = v.z;
    slab[(c * 64 + w4s + 3) * 4 + h] = v.w;
  }

  // ---- t-part into racc (overlaps slab staging; no slab use here) ----
  f32x4 racc[8];
#pragma unroll
  for (int ci = 0; ci < 8; ++ci) racc[ci] = (f32x4){0.f, 0.f, 0.f, 0.f};

#pragma unroll 2
  for (int s = 0; s < 8; ++s) {
    const float* pa = Ab + (size_t)s * THW + h0 * 64 + wq;
    f32x4 a;
    a.x = pa[0];
    a.y = pa[64];
    a.z = pa[128];
    a.w = pa[192];
#pragma unroll
    for (int ci = 0; ci < 8; ++ci) {
      const int c = cg + ci * 4;
      const float* pp = &PV[pvh + (size_t)c * THW + (size_t)s * HWP + h0 * 64 + wq];
      f32x4 v;
      v.x = pp[0];
      v.y = pp[64];
      v.z = pp[128];
      v.w = pp[192];
      racc[ci] += a * v;
    }
  }
  __syncthreads();

  // ---- w-part: weight row per (p, lane) ----
#pragma unroll 4
  for (int p = 0; p < 64; ++p) {
    const int row = 71 + p - (wq <= p ? 1 : 0);  // 70..133, in-bounds always
    const float* pa = Ab + (size_t)row * THW + h0 * 64 + wq;
    f32x4 a;
    a.x = pa[0];
    a.y = pa[64];
    a.z = pa[128];
    a.w = pa[192];
    if (p == wq) a = (f32x4){0.f, 0.f, 0.f, 0.f};
#pragma unroll
    for (int ci = 0; ci < 8; ++ci) {
      const f32x4 v = *(const f32x4*)&slab[(cg + ci * 4) * 256 + p * 4];
      racc[ci] += a * v;
    }
  }

  // ---- store (single write; attn_h RMWs the h-part on top) ----
#pragma unroll
  for (int ci = 0; ci < 8; ++ci) {
    const int c = cg + ci * 4;
#pragma unroll
    for (int hh = 0; hh < 4; ++hh)
      O[pvh + (size_t)c * THW + (size_t)tq * HWP + (h0 + hh) * 64 + wq] = racc[ci][hh];
  }
}

// ---------------------------------------------------------------------------
// h axis v8, RMW on O: NO LDS, NO BARRIERS. Diagnosis across R2-R10: traffic
// -4x flat, occupancy x2 flat — the binding cost was hipcc's forced
// `s_waitcnt vmcnt(0)` before every s_barrier (32 barriers/block, ~nothing
// between them): no load could ever span a chunk boundary. v8 drops the pv
// LDS slab; each wave reads pv directly from global (f32x4, lanes =
// 4 c-rows x full w = 1KB contiguous per instr; all 8 waves walk the same
// 256KB pv slice -> L1/L2-hot). Whole p-loop is one barrier-free stream of
// independent loads — the regime this machine runs at 87% HBM (fill kernel).
// pv L2-side re-read (x8 waves) ~1GB: R5 proved L2-side traffic is cheap.
// Accumulation order unchanged (acc from O, p ascending) -> bitwise same.
// ---------------------------------------------------------------------------
__global__ __launch_bounds__(512) void attn_h(
    const float* __restrict__ A, const float* __restrict__ PV,
    float* __restrict__ O) {
  const int b = blockIdx.x;  // hd + 8*(chb + 2*(qb + 4*tq)), grid 512
  const int hd = b & 7;
  const int chb = (b >> 3) & 1;
  const int qb = (b >> 4) & 3;
  const int tq = b >> 6;  // 0..7
  const int tid = threadIdx.x;
  const int lane = tid & 63;
  const int wv = tid >> 6;         // 0..7
  const int w4 = (lane & 15) * 4;  // w float-offset (f32x4)
  const int cl = lane >> 4;        // 0..3
  const int q0 = qb * 16 + wv * 2;
  const int c0 = chb * 16;

  const float* __restrict__ Ab = A + (size_t)hd * SS * THW + (size_t)tq * HWP;
  const size_t pvh = (size_t)hd * 32 * THW;

  // per-g pv row base: PV[pvh + c*THW + tq*HWP + w4], c = c0 + g*4 + cl
  const float* __restrict__ pvg[4];
#pragma unroll
  for (int g = 0; g < 4; ++g)
    pvg[g] = PV + pvh + (size_t)(c0 + g * 4 + cl) * THW + (size_t)tq * HWP + w4;

  // init acc from O (t+w part, RMW)
  f32x4 acc[2][4];  // [qi][g]
#pragma unroll
  for (int qi = 0; qi < 2; ++qi) {
    const int q = q0 + qi;
#pragma unroll
    for (int g = 0; g < 4; ++g) {
      const int c = c0 + g * 4 + cl;
      acc[qi][g] =
          *(const f32x4*)&O[pvh + (size_t)c * THW + (size_t)tq * HWP + q * 64 + w4];
    }
  }

  // ---- h axis: barrier-free independent load-FMA stream over p ----
#pragma unroll 2
  for (int p = 0; p < 64; ++p) {
    f32x4 a[2];
#pragma unroll
    for (int qi = 0; qi < 2; ++qi) {
      const int q = q0 + qi;
      const int row = p - (q < p ? 1 : 0);  // 0..63 (p==q load masked)
      f32x4 av = *(const f32x4*)&Ab[(size_t)(8 + row) * THW + q * 64 + w4];
      if (q == p) av = (f32x4){0.f, 0.f, 0.f, 0.f};
      a[qi] = av;
    }
    f32x4 v[4];
#pragma unroll
    for (int g = 0; g < 4; ++g)
      v[g] = *(const f32x4*)&pvg[g][p * 64];
#pragma unroll
    for (int qi = 0; qi < 2; ++qi)
#pragma unroll
      for (int g = 0; g < 4; ++g)
        acc[qi][g] += a[qi] * v[g];
  }

  // ---- store (t + w + h) ----
#pragma unroll
  for (int qi = 0; qi < 2; ++qi) {
    const int q = q0 + qi;
#pragma unroll
    for (int g = 0; g < 4; ++g) {
      const int c = c0 + g * 4 + cl;
      *(f32x4*)&O[pvh + (size_t)c * THW + (size_t)tq * HWP + q * 64 + w4] =
          acc[qi][g];
    }
  }
}

extern "C" void kernel_launch(void* const* d_in, const int* in_sizes, int n_in,
                              void* d_out, int out_size, void* d_ws, size_t ws_size,
                              hipStream_t stream) {
  const float* A = (const float*)d_in[0];     // [8*134][8][64][64]
  const float* V = (const float*)d_in[1];     // [256][8][64][64]
  const float* W = (const float*)d_in[2];     // [256][256] (o, c)
  const float* bias = (const float*)d_in[3];  // [256]
  float* out = (float*)d_out;                 // [256][8][64][64]
  float* pv = (float*)d_ws;                   // 32 MB scratch: pv[o][t][h][w]

  unsigned short* Wbf = (unsigned short*)d_out;  // temp 128 KB, dead after conv

  w2bf<<<dim3(64), 256, 0, stream>>>(W, Wbf);
  conv1x1_v4<<<dim3(256), 512, 0, stream>>>(V, Wbf, bias, pv);
  attn_tw<<<dim3(1024), 256, 0, stream>>>(A, pv, out);
  attn_h<<<dim3(512), 512, 0, stream>>>(A, pv, out);
}

// Round 12
// 341.247 us; speedup vs baseline: 1.0428x; 1.0428x over previous
//
#include <hip/hip_runtime.h>

// Shapes (fixed per setup_inputs): n=1, C=256, t=8, h=64, w=64, heads=8, S=134
#define SS   134
#define HWP  4096     // h*w
#define THW  32768    // t*h*w

typedef float f32x4 __attribute__((ext_vector_type(4)));
typedef short bf16x8 __attribute__((ext_vector_type(8)));
typedef short bf16x4 __attribute__((ext_vector_type(4)));

__device__ __forceinline__ unsigned short f2bf(float f) {
  unsigned int u = __float_as_uint(f);
  u += 0x7fff + ((u >> 16) & 1);  // RNE (inputs are finite normals)
  return (unsigned short)(u >> 16);
}

// ---------------------------------------------------------------------------
// W -> bf16, once. Wbf lives in d_out (128 KB): attn_tw fully overwrites O
// afterwards; stream order (w2bf -> conv -> attn_tw) makes aliasing safe.
// ---------------------------------------------------------------------------
__global__ __launch_bounds__(256) void w2bf(const float* __restrict__ W,
                                            unsigned short* __restrict__ Wbf) {
  const int i = (blockIdx.x * 256 + threadIdx.x) * 4;  // grid 64 -> 65536
  const float4 w4 = *(const float4*)&W[i];
  bf16x4 b;
  b.x = (short)f2bf(w4.x);
  b.y = (short)f2bf(w4.y);
  b.z = (short)f2bf(w4.z);
  b.w = (short)f2bf(w4.w);
  *(bf16x4*)&Wbf[i] = b;
}

// ---------------------------------------------------------------------------
// 1x1 conv v4 (unchanged): W staged once into 130KB LDS, V dbuf.
// ---------------------------------------------------------------------------
__global__ __launch_bounds__(512) void conv1x1_v4(
    const float* __restrict__ V, const unsigned short* __restrict__ Wbf,
    const float* __restrict__ bias, float* __restrict__ PV) {
  __shared__ unsigned short sW[256 * 260];   // 130 KB, row stride 260
  __shared__ unsigned short sV[2][128 * 40]; // [buf][x][c], 2 x 10 KB
  const int tid = threadIdx.x;
  const int x0 = blockIdx.x * 128;  // grid 256
  const int lane = tid & 63;
  const int wv = tid >> 6;   // 0..7
  const int m = lane & 15;   // MFMA free-dim index
  const int q = lane >> 4;   // MFMA quad 0..3

  {
    const int o = tid >> 1;
    const int half = (tid & 1) * 128;
#pragma unroll
    for (int r = 0; r < 16; ++r)
      *(bf16x8*)&sW[o * 260 + half + r * 8] =
          *(const bf16x8*)&Wbf[o * 256 + half + r * 8];
  }

  const int c_s = tid >> 4;
  const int x8 = (tid & 15) * 8;
  const float* __restrict__ vstage = V + (size_t)c_s * THW + x0 + x8;

  {
    const float4 va = *(const float4*)&vstage[0];
    const float4 vb = *(const float4*)&vstage[4];
    sV[0][(x8 + 0) * 40 + c_s] = f2bf(va.x);
    sV[0][(x8 + 1) * 40 + c_s] = f2bf(va.y);
    sV[0][(x8 + 2) * 40 + c_s] = f2bf(va.z);
    sV[0][(x8 + 3) * 40 + c_s] = f2bf(va.w);
    sV[0][(x8 + 4) * 40 + c_s] = f2bf(vb.x);
    sV[0][(x8 + 5) * 40 + c_s] = f2bf(vb.y);
    sV[0][(x8 + 6) * 40 + c_s] = f2bf(vb.z);
    sV[0][(x8 + 7) * 40 + c_s] = f2bf(vb.w);
  }
  __syncthreads();

  f32x4 acc[2][8];
#pragma unroll
  for (int i = 0; i < 2; ++i)
#pragma unroll
    for (int j = 0; j < 8; ++j)
      acc[i][j] = (f32x4){0.f, 0.f, 0.f, 0.f};

  for (int kk = 0; kk < 8; ++kk) {
    const int cur = kk & 1;
    float4 pva, pvb;
    if (kk < 7) {
      pva = *(const float4*)&vstage[(size_t)(kk + 1) * 32 * THW];
      pvb = *(const float4*)&vstage[(size_t)(kk + 1) * 32 * THW + 4];
    }
    bf16x8 fa[2], fb[8];
#pragma unroll
    for (int i = 0; i < 2; ++i)
      fa[i] = *(const bf16x8*)&sW[(wv * 32 + i * 16 + m) * 260 + kk * 32 + q * 8];
#pragma unroll
    for (int j = 0; j < 8; ++j)
      fb[j] = *(const bf16x8*)&sV[cur][(j * 16 + m) * 40 + q * 8];
#pragma unroll
    for (int i = 0; i < 2; ++i)
#pragma unroll
      for (int j = 0; j < 8; ++j)
        acc[i][j] = __builtin_amdgcn_mfma_f32_16x16x32_bf16(fa[i], fb[j], acc[i][j], 0, 0, 0);
    if (kk < 7) {
      const int nb = cur ^ 1;
      sV[nb][(x8 + 0) * 40 + c_s] = f2bf(pva.x);
      sV[nb][(x8 + 1) * 40 + c_s] = f2bf(pva.y);
      sV[nb][(x8 + 2) * 40 + c_s] = f2bf(pva.z);
      sV[nb][(x8 + 3) * 40 + c_s] = f2bf(pva.w);
      sV[nb][(x8 + 4) * 40 + c_s] = f2bf(pvb.x);
      sV[nb][(x8 + 5) * 40 + c_s] = f2bf(pvb.y);
      sV[nb][(x8 + 6) * 40 + c_s] = f2bf(pvb.z);
      sV[nb][(x8 + 7) * 40 + c_s] = f2bf(pvb.w);
    }
    __syncthreads();
  }

#pragma unroll
  for (int i = 0; i < 2; ++i) {
#pragma unroll
    for (int r = 0; r < 4; ++r) {
      const int o = wv * 32 + i * 16 + q * 4 + r;
      const float bo = bias[o];
#pragma unroll
      for (int j = 0; j < 8; ++j)
        PV[(size_t)o * THW + x0 + j * 16 + m] = acc[i][j][r] + bo;
    }
  }
}

// ---------------------------------------------------------------------------
// t + w fused, v2: RE-LANED for full-payload loads. R11 diagnosis: all attn
// kernels are Little's-law bound (outstanding-bytes x latency); the old tw
// assembled h-gathers from SCALAR dword loads (256B/wave-instr, ~600
// VMEM/thread). New lane map: hh = lane>>4 (4 h), w4 = (lane&15)*4 (full w
// as f32x4) -> every A/pv/O access is f32x4 with 1KB/wave payload (~216
// VMEM/thread, 4x bytes per instr). racc[ci] = f32x4 over w at h=h0+hh.
// w-part row select now varies per f32x4 component: load rows 70+p and
// 71+p (hi clamped at 133; unused at p==63) and cndmask per component.
// Per-output accumulation order unchanged (s asc, then p asc) -> bitwise
// identical to R10. O written once (attn_h RMWs h-part on top).
// ---------------------------------------------------------------------------
__global__ __launch_bounds__(256) void attn_tw(
    const float* __restrict__ A, const float* __restrict__ PV,
    float* __restrict__ O) {
  const int b = blockIdx.x;  // hb + 16*tq + 128*hd, grid 1024
  const int hb = b & 15;
  const int tq = (b >> 4) & 7;
  const int hd = b >> 7;
  const int tid = threadIdx.x;
  const int lane = tid & 63;
  const int hh = lane >> 4;        // 0..3 (h within strip)
  const int w4 = (lane & 15) * 4;  // w float offset
  const int cg = tid >> 6;         // 0..3
  const int h0 = hb * 4;

  __shared__ float slab[32 * 64 * 4];  // [c][pw][h4] = 32 KB

  const float* __restrict__ Ab = A + (size_t)hd * SS * THW + (size_t)tq * HWP;
  const size_t pvh = (size_t)hd * 32 * THW;
  const int hw = (h0 + hh) * 64 + w4;  // per-lane (h,w) offset within a plane

  // ---- stage pv w-slab (transpose w<->h minor dims), c = 0..31 ----
#pragma unroll
  for (int i = 0; i < 8; ++i) {
    const int fid = tid + i * 256;     // 0..2047
    const int w4s = (fid & 15) * 4;    // 0..60
    const int h = (fid >> 4) & 3;      // 0..3
    const int c = fid >> 6;            // 0..31
    const f32x4 v =
        *(const f32x4*)&PV[pvh + (size_t)c * THW + (size_t)tq * HWP + (h0 + h) * 64 + w4s];
    slab[(c * 64 + w4s + 0) * 4 + h] = v.x;
    slab[(c * 64 + w4s + 1) * 4 + h] = v.y;
    slab[(c * 64 + w4s + 2) * 4 + h] = v.z;
    slab[(c * 64 + w4s + 3) * 4 + h] = v.w;
  }

  // ---- t-part into racc (overlaps slab staging; no slab use here) ----
  // racc[ci] (f32x4 over w) at (c = cg + ci*4, h0+hh)
  f32x4 racc[8];
#pragma unroll
  for (int ci = 0; ci < 8; ++ci) racc[ci] = (f32x4){0.f, 0.f, 0.f, 0.f};

#pragma unroll 2
  for (int s = 0; s < 8; ++s) {
    const f32x4 a = *(const f32x4*)&Ab[(size_t)s * THW + hw];
#pragma unroll
    for (int ci = 0; ci < 8; ++ci) {
      const int c = cg + ci * 4;
      const f32x4 v = *(const f32x4*)&PV[pvh + (size_t)c * THW + (size_t)s * HWP + hw];
      racc[ci] += a * v;
    }
  }
  __syncthreads();

  // ---- w-part: per p, rows 70+p (wq<=p) / 71+p (wq>p), component select ---
#pragma unroll 2
  for (int p = 0; p < 64; ++p) {
    const int rHi = (p < 63) ? (71 + p) : 133;  // unused at p==63, clamp OOB
    const f32x4 aLo = *(const f32x4*)&Ab[(size_t)(70 + p) * THW + hw];
    const f32x4 aHi = *(const f32x4*)&Ab[(size_t)rHi * THW + hw];
    f32x4 a;
#pragma unroll
    for (int j = 0; j < 4; ++j) {
      const int wqj = w4 + j;
      const float sv = (wqj <= p) ? aLo[j] : aHi[j];
      a[j] = (wqj == p) ? 0.f : sv;
    }
#pragma unroll
    for (int ci = 0; ci < 8; ++ci) {
      const float v = slab[((cg + ci * 4) * 64 + p) * 4 + hh];  // bcast x16
      racc[ci] += a * v;
    }
  }

  // ---- store (single 1KB-coalesced write per (ci)) ----
#pragma unroll
  for (int ci = 0; ci < 8; ++ci) {
    const int c = cg + ci * 4;
    *(f32x4*)&O[pvh + (size_t)c * THW + (size_t)tq * HWP + hw] = racc[ci];
  }
}

// ---------------------------------------------------------------------------
// h axis v9, RMW on O: barrier-free (R11) + DEEP UNROLL. R11 closed the
// model: BW = outstanding x 128B / 600cyc; VGPR=60 meant only ~12 loads in
// flight/wave -> 25B/cyc/CU = the measured 1.1TB/s. unroll 4 targets ~24
// in flight (VGPR ~130-160; even if blocks/CU drops 2->1, outstanding/CU
// rises). Accumulation order unchanged (acc from O, p asc) -> bitwise same.
// ---------------------------------------------------------------------------
__global__ __launch_bounds__(512) void attn_h(
    const float* __restrict__ A, const float* __restrict__ PV,
    float* __restrict__ O) {
  const int b = blockIdx.x;  // hd + 8*(chb + 2*(qb + 4*tq)), grid 512
  const int hd = b & 7;
  const int chb = (b >> 3) & 1;
  const int qb = (b >> 4) & 3;
  const int tq = b >> 6;  // 0..7
  const int tid = threadIdx.x;
  const int lane = tid & 63;
  const int wv = tid >> 6;         // 0..7
  const int w4 = (lane & 15) * 4;  // w float-offset (f32x4)
  const int cl = lane >> 4;        // 0..3
  const int q0 = qb * 16 + wv * 2;
  const int c0 = chb * 16;

  const float* __restrict__ Ab = A + (size_t)hd * SS * THW + (size_t)tq * HWP;
  const size_t pvh = (size_t)hd * 32 * THW;

  // per-g pv row base: PV[pvh + c*THW + tq*HWP + w4], c = c0 + g*4 + cl
  const float* __restrict__ pvg[4];
#pragma unroll
  for (int g = 0; g < 4; ++g)
    pvg[g] = PV + pvh + (size_t)(c0 + g * 4 + cl) * THW + (size_t)tq * HWP + w4;

  // init acc from O (t+w part, RMW)
  f32x4 acc[2][4];  // [qi][g]
#pragma unroll
  for (int qi = 0; qi < 2; ++qi) {
    const int q = q0 + qi;
#pragma unroll
    for (int g = 0; g < 4; ++g) {
      const int c = c0 + g * 4 + cl;
      acc[qi][g] =
          *(const f32x4*)&O[pvh + (size_t)c * THW + (size_t)tq * HWP + q * 64 + w4];
    }
  }

  // ---- h axis: barrier-free stream, deep-unrolled for MLP ----
#pragma unroll 4
  for (int p = 0; p < 64; ++p) {
    f32x4 a[2];
#pragma unroll
    for (int qi = 0; qi < 2; ++qi) {
      const int q = q0 + qi;
      const int row = p - (q < p ? 1 : 0);  // 0..63 (p==q load masked)
      f32x4 av = *(const f32x4*)&Ab[(size_t)(8 + row) * THW + q * 64 + w4];
      if (q == p) av = (f32x4){0.f, 0.f, 0.f, 0.f};
      a[qi] = av;
    }
    f32x4 v[4];
#pragma unroll
    for (int g = 0; g < 4; ++g)
      v[g] = *(const f32x4*)&pvg[g][p * 64];
#pragma unroll
    for (int qi = 0; qi < 2; ++qi)
#pragma unroll
      for (int g = 0; g < 4; ++g)
        acc[qi][g] += a[qi] * v[g];
  }

  // ---- store (t + w + h) ----
#pragma unroll
  for (int qi = 0; qi < 2; ++qi) {
    const int q = q0 + qi;
#pragma unroll
    for (int g = 0; g < 4; ++g) {
      const int c = c0 + g * 4 + cl;
      *(f32x4*)&O[pvh + (size_t)c * THW + (size_t)tq * HWP + q * 64 + w4] =
          acc[qi][g];
    }
  }
}

extern "C" void kernel_launch(void* const* d_in, const int* in_sizes, int n_in,
                              void* d_out, int out_size, void* d_ws, size_t ws_size,
                              hipStream_t stream) {
  const float* A = (const float*)d_in[0];     // [8*134][8][64][64]
  const float* V = (const float*)d_in[1];     // [256][8][64][64]
  const float* W = (const float*)d_in[2];     // [256][256] (o, c)
  const float* bias = (const float*)d_in[3];  // [256]
  float* out = (float*)d_out;                 // [256][8][64][64]
  float* pv = (float*)d_ws;                   // 32 MB scratch: pv[o][t][h][w]

  unsigned short* Wbf = (unsigned short*)d_out;  // temp 128 KB, dead after conv

  w2bf<<<dim3(64), 256, 0, stream>>>(W, Wbf);
  conv1x1_v4<<<dim3(256), 512, 0, stream>>>(V, Wbf, bias, pv);
  attn_tw<<<dim3(1024), 256, 0, stream>>>(A, pv, out);
  attn_h<<<dim3(512), 512, 0, stream>>>(A, pv, out);
}

// Round 13
// 335.026 us; speedup vs baseline: 1.0622x; 1.0186x over previous
//
#include <hip/hip_runtime.h>

// Shapes (fixed per setup_inputs): n=1, C=256, t=8, h=64, w=64, heads=8, S=134
#define SS   134
#define HWP  4096     // h*w
#define THW  32768    // t*h*w

typedef float f32x4 __attribute__((ext_vector_type(4)));
typedef short bf16x8 __attribute__((ext_vector_type(8)));
typedef short bf16x4 __attribute__((ext_vector_type(4)));

__device__ __forceinline__ unsigned short f2bf(float f) {
  unsigned int u = __float_as_uint(f);
  u += 0x7fff + ((u >> 16) & 1);  // RNE (inputs are finite normals)
  return (unsigned short)(u >> 16);
}

// ---------------------------------------------------------------------------
// W -> bf16, once. Wbf lives in d_out (128 KB): attn_tw fully overwrites O
// afterwards; stream order (w2bf -> conv -> attn_tw) makes aliasing safe.
// ---------------------------------------------------------------------------
__global__ __launch_bounds__(256) void w2bf(const float* __restrict__ W,
                                            unsigned short* __restrict__ Wbf) {
  const int i = (blockIdx.x * 256 + threadIdx.x) * 4;  // grid 64 -> 65536
  const float4 w4 = *(const float4*)&W[i];
  bf16x4 b;
  b.x = (short)f2bf(w4.x);
  b.y = (short)f2bf(w4.y);
  b.z = (short)f2bf(w4.z);
  b.w = (short)f2bf(w4.w);
  *(bf16x4*)&Wbf[i] = b;
}

// ---------------------------------------------------------------------------
// 1x1 conv v4 (unchanged): W staged once into 130KB LDS, V dbuf.
// ---------------------------------------------------------------------------
__global__ __launch_bounds__(512) void conv1x1_v4(
    const float* __restrict__ V, const unsigned short* __restrict__ Wbf,
    const float* __restrict__ bias, float* __restrict__ PV) {
  __shared__ unsigned short sW[256 * 260];   // 130 KB, row stride 260
  __shared__ unsigned short sV[2][128 * 40]; // [buf][x][c], 2 x 10 KB
  const int tid = threadIdx.x;
  const int x0 = blockIdx.x * 128;  // grid 256
  const int lane = tid & 63;
  const int wv = tid >> 6;   // 0..7
  const int m = lane & 15;   // MFMA free-dim index
  const int q = lane >> 4;   // MFMA quad 0..3

  {
    const int o = tid >> 1;
    const int half = (tid & 1) * 128;
#pragma unroll
    for (int r = 0; r < 16; ++r)
      *(bf16x8*)&sW[o * 260 + half + r * 8] =
          *(const bf16x8*)&Wbf[o * 256 + half + r * 8];
  }

  const int c_s = tid >> 4;
  const int x8 = (tid & 15) * 8;
  const float* __restrict__ vstage = V + (size_t)c_s * THW + x0 + x8;

  {
    const float4 va = *(const float4*)&vstage[0];
    const float4 vb = *(const float4*)&vstage[4];
    sV[0][(x8 + 0) * 40 + c_s] = f2bf(va.x);
    sV[0][(x8 + 1) * 40 + c_s] = f2bf(va.y);
    sV[0][(x8 + 2) * 40 + c_s] = f2bf(va.z);
    sV[0][(x8 + 3) * 40 + c_s] = f2bf(va.w);
    sV[0][(x8 + 4) * 40 + c_s] = f2bf(vb.x);
    sV[0][(x8 + 5) * 40 + c_s] = f2bf(vb.y);
    sV[0][(x8 + 6) * 40 + c_s] = f2bf(vb.z);
    sV[0][(x8 + 7) * 40 + c_s] = f2bf(vb.w);
  }
  __syncthreads();

  f32x4 acc[2][8];
#pragma unroll
  for (int i = 0; i < 2; ++i)
#pragma unroll
    for (int j = 0; j < 8; ++j)
      acc[i][j] = (f32x4){0.f, 0.f, 0.f, 0.f};

  for (int kk = 0; kk < 8; ++kk) {
    const int cur = kk & 1;
    float4 pva, pvb;
    if (kk < 7) {
      pva = *(const float4*)&vstage[(size_t)(kk + 1) * 32 * THW];
      pvb = *(const float4*)&vstage[(size_t)(kk + 1) * 32 * THW + 4];
    }
    bf16x8 fa[2], fb[8];
#pragma unroll
    for (int i = 0; i < 2; ++i)
      fa[i] = *(const bf16x8*)&sW[(wv * 32 + i * 16 + m) * 260 + kk * 32 + q * 8];
#pragma unroll
    for (int j = 0; j < 8; ++j)
      fb[j] = *(const bf16x8*)&sV[cur][(j * 16 + m) * 40 + q * 8];
#pragma unroll
    for (int i = 0; i < 2; ++i)
#pragma unroll
      for (int j = 0; j < 8; ++j)
        acc[i][j] = __builtin_amdgcn_mfma_f32_16x16x32_bf16(fa[i], fb[j], acc[i][j], 0, 0, 0);
    if (kk < 7) {
      const int nb = cur ^ 1;
      sV[nb][(x8 + 0) * 40 + c_s] = f2bf(pva.x);
      sV[nb][(x8 + 1) * 40 + c_s] = f2bf(pva.y);
      sV[nb][(x8 + 2) * 40 + c_s] = f2bf(pva.z);
      sV[nb][(x8 + 3) * 40 + c_s] = f2bf(pva.w);
      sV[nb][(x8 + 4) * 40 + c_s] = f2bf(pvb.x);
      sV[nb][(x8 + 5) * 40 + c_s] = f2bf(pvb.y);
      sV[nb][(x8 + 6) * 40 + c_s] = f2bf(pvb.z);
      sV[nb][(x8 + 7) * 40 + c_s] = f2bf(pvb.w);
    }
    __syncthreads();
  }

#pragma unroll
  for (int i = 0; i < 2; ++i) {
#pragma unroll
    for (int r = 0; r < 4; ++r) {
      const int o = wv * 32 + i * 16 + q * 4 + r;
      const float bo = bias[o];
#pragma unroll
      for (int j = 0; j < 8; ++j)
        PV[(size_t)o * THW + x0 + j * 16 + m] = acc[i][j][r] + bo;
    }
  }
}

// ---------------------------------------------------------------------------
// t + w fused, v3: EXPLICIT LOAD BATCHING. R12 lesson: #pragma unroll does
// not deepen the load pipeline (VGPR stayed 60; compiler serialized loads).
// v3 forces MLP with two-phase batch bodies: issue-all-loads into named
// f32x4 arrays, then consume. t-part: depth 2 (18 loads in flight).
// w-part: depth 4 (8 loads in flight). Masks applied in consume phase.
// Accumulation order per output unchanged (s asc, p asc) -> bitwise = R12.
// ---------------------------------------------------------------------------
__global__ __launch_bounds__(256) void attn_tw(
    const float* __restrict__ A, const float* __restrict__ PV,
    float* __restrict__ O) {
  const int b = blockIdx.x;  // hb + 16*tq + 128*hd, grid 1024
  const int hb = b & 15;
  const int tq = (b >> 4) & 7;
  const int hd = b >> 7;
  const int tid = threadIdx.x;
  const int lane = tid & 63;
  const int hh = lane >> 4;        // 0..3 (h within strip)
  const int w4 = (lane & 15) * 4;  // w float offset
  const int cg = tid >> 6;         // 0..3
  const int h0 = hb * 4;

  __shared__ float slab[32 * 64 * 4];  // [c][pw][h4] = 32 KB

  const float* __restrict__ Ab = A + (size_t)hd * SS * THW + (size_t)tq * HWP;
  const size_t pvh = (size_t)hd * 32 * THW;
  const int hw = (h0 + hh) * 64 + w4;  // per-lane (h,w) offset within a plane

  // ---- stage pv w-slab (transpose w<->h minor dims), c = 0..31 ----
#pragma unroll
  for (int i = 0; i < 8; ++i) {
    const int fid = tid + i * 256;     // 0..2047
    const int w4s = (fid & 15) * 4;    // 0..60
    const int h = (fid >> 4) & 3;      // 0..3
    const int c = fid >> 6;            // 0..31
    const f32x4 v =
        *(const f32x4*)&PV[pvh + (size_t)c * THW + (size_t)tq * HWP + (h0 + h) * 64 + w4s];
    slab[(c * 64 + w4s + 0) * 4 + h] = v.x;
    slab[(c * 64 + w4s + 1) * 4 + h] = v.y;
    slab[(c * 64 + w4s + 2) * 4 + h] = v.z;
    slab[(c * 64 + w4s + 3) * 4 + h] = v.w;
  }

  // ---- t-part, explicit depth-2 batches (9 loads per s, 18 in flight) ----
  f32x4 racc[8];
#pragma unroll
  for (int ci = 0; ci < 8; ++ci) racc[ci] = (f32x4){0.f, 0.f, 0.f, 0.f};

  for (int sb = 0; sb < 8; sb += 2) {
    f32x4 aT[2], vT[2][8];
#pragma unroll
    for (int ss = 0; ss < 2; ++ss) {
      const int s = sb + ss;
      aT[ss] = *(const f32x4*)&Ab[(size_t)s * THW + hw];
#pragma unroll
      for (int ci = 0; ci < 8; ++ci) {
        const int c = cg + ci * 4;
        vT[ss][ci] = *(const f32x4*)&PV[pvh + (size_t)c * THW + (size_t)s * HWP + hw];
      }
    }
#pragma unroll
    for (int ss = 0; ss < 2; ++ss)
#pragma unroll
      for (int ci = 0; ci < 8; ++ci)
        racc[ci] += aT[ss] * vT[ss][ci];
  }
  __syncthreads();

  // ---- w-part, explicit depth-4 batches (8 global loads in flight) ----
  for (int pb = 0; pb < 64; pb += 4) {
    f32x4 lo[4], hi[4];
#pragma unroll
    for (int pp = 0; pp < 4; ++pp) {
      const int p = pb + pp;
      const int rHi = (p < 63) ? (71 + p) : 133;  // unused at p==63, clamp OOB
      lo[pp] = *(const f32x4*)&Ab[(size_t)(70 + p) * THW + hw];
      hi[pp] = *(const f32x4*)&Ab[(size_t)rHi * THW + hw];
    }
#pragma unroll
    for (int pp = 0; pp < 4; ++pp) {
      const int p = pb + pp;
      f32x4 a;
#pragma unroll
      for (int j = 0; j < 4; ++j) {
        const int wqj = w4 + j;
        const float sv = (wqj <= p) ? lo[pp][j] : hi[pp][j];
        a[j] = (wqj == p) ? 0.f : sv;
      }
#pragma unroll
      for (int ci = 0; ci < 8; ++ci) {
        const float v = slab[((cg + ci * 4) * 64 + p) * 4 + hh];  // bcast x16
        racc[ci] += a * v;
      }
    }
  }

  // ---- store (single 1KB-coalesced write per (ci)) ----
#pragma unroll
  for (int ci = 0; ci < 8; ++ci) {
    const int c = cg + ci * 4;
    *(f32x4*)&O[pvh + (size_t)c * THW + (size_t)tq * HWP + hw] = racc[ci];
  }
}

// ---------------------------------------------------------------------------
// h axis v10, RMW on O: barrier-free + EXPLICIT depth-4 load batching.
// R12 proved #pragma unroll leaves VGPR at 60 (loads serialized). v10
// forces 24 loads in flight per wave via named buffers aB[4][2], vB[4][4]
// (issue phase branch-free; q==p mask applied in consume phase).
// Expected VGPR ~150 (check counters; WRITE_SIZE must stay 32768 = no
// spill). Accumulation order unchanged (acc from O, p asc) -> bitwise same.
// ---------------------------------------------------------------------------
__global__ __launch_bounds__(512) void attn_h(
    const float* __restrict__ A, const float* __restrict__ PV,
    float* __restrict__ O) {
  const int b = blockIdx.x;  // hd + 8*(chb + 2*(qb + 4*tq)), grid 512
  const int hd = b & 7;
  const int chb = (b >> 3) & 1;
  const int qb = (b >> 4) & 3;
  const int tq = b >> 6;  // 0..7
  const int tid = threadIdx.x;
  const int lane = tid & 63;
  const int wv = tid >> 6;         // 0..7
  const int w4 = (lane & 15) * 4;  // w float-offset (f32x4)
  const int cl = lane >> 4;        // 0..3
  const int q0 = qb * 16 + wv * 2;
  const int c0 = chb * 16;

  const float* __restrict__ Ab = A + (size_t)hd * SS * THW + (size_t)tq * HWP;
  const size_t pvh = (size_t)hd * 32 * THW;

  // per-g pv row base: PV[pvh + c*THW + tq*HWP + w4], c = c0 + g*4 + cl
  const float* __restrict__ pvg[4];
#pragma unroll
  for (int g = 0; g < 4; ++g)
    pvg[g] = PV + pvh + (size_t)(c0 + g * 4 + cl) * THW + (size_t)tq * HWP + w4;

  // init acc from O (t+w part, RMW)
  f32x4 acc[2][4];  // [qi][g]
#pragma unroll
  for (int qi = 0; qi < 2; ++qi) {
    const int q = q0 + qi;
#pragma unroll
    for (int g = 0; g < 4; ++g) {
      const int c = c0 + g * 4 + cl;
      acc[qi][g] =
          *(const f32x4*)&O[pvh + (size_t)c * THW + (size_t)tq * HWP + q * 64 + w4];
    }
  }

  // ---- h axis: explicit depth-4 batches, 24 loads in flight ----
  for (int pb = 0; pb < 64; pb += 4) {
    f32x4 aB[4][2], vB[4][4];
#pragma unroll
    for (int pp = 0; pp < 4; ++pp) {
      const int p = pb + pp;
#pragma unroll
      for (int qi = 0; qi < 2; ++qi) {
        const int q = q0 + qi;
        const int row = p - (q < p ? 1 : 0);  // 0..63
        aB[pp][qi] = *(const f32x4*)&Ab[(size_t)(8 + row) * THW + q * 64 + w4];
      }
#pragma unroll
      for (int g = 0; g < 4; ++g)
        vB[pp][g] = *(const f32x4*)&pvg[g][p * 64];
    }
#pragma unroll
    for (int pp = 0; pp < 4; ++pp) {
      const int p = pb + pp;
#pragma unroll
      for (int qi = 0; qi < 2; ++qi) {
        f32x4 av = aB[pp][qi];
        if (q0 + qi == p) av = (f32x4){0.f, 0.f, 0.f, 0.f};
#pragma unroll
        for (int g = 0; g < 4; ++g)
          acc[qi][g] += av * vB[pp][g];
      }
    }
  }

  // ---- store (t + w + h) ----
#pragma unroll
  for (int qi = 0; qi < 2; ++qi) {
    const int q = q0 + qi;
#pragma unroll
    for (int g = 0; g < 4; ++g) {
      const int c = c0 + g * 4 + cl;
      *(f32x4*)&O[pvh + (size_t)c * THW + (size_t)tq * HWP + q * 64 + w4] =
          acc[qi][g];
    }
  }
}

extern "C" void kernel_launch(void* const* d_in, const int* in_sizes, int n_in,
                              void* d_out, int out_size, void* d_ws, size_t ws_size,
                              hipStream_t stream) {
  const float* A = (const float*)d_in[0];     // [8*134][8][64][64]
  const float* V = (const float*)d_in[1];     // [256][8][64][64]
  const float* W = (const float*)d_in[2];     // [256][256] (o, c)
  const float* bias = (const float*)d_in[3];  // [256]
  float* out = (float*)d_out;                 // [256][8][64][64]
  float* pv = (float*)d_ws;                   // 32 MB scratch: pv[o][t][h][w]

  unsigned short* Wbf = (unsigned short*)d_out;  // temp 128 KB, dead after conv

  w2bf<<<dim3(64), 256, 0, stream>>>(W, Wbf);
  conv1x1_v4<<<dim3(256), 512, 0, stream>>>(V, Wbf, bias, pv);
  attn_tw<<<dim3(1024), 256, 0, stream>>>(A, pv, out);
  attn_h<<<dim3(512), 512, 0, stream>>>(A, pv, out);
}